// Round 1
// 220.196 us; speedup vs baseline: 1.0245x; 1.0245x over previous
//
#include <hip/hip_runtime.h>
#include <cstdint>

#define DEV static __device__ __forceinline__

typedef __bf16 bf16x8 __attribute__((ext_vector_type(8)));
typedef __bf16 bf16x4 __attribute__((ext_vector_type(4)));
typedef short  s16x4  __attribute__((ext_vector_type(4)));
typedef float  f32x4  __attribute__((ext_vector_type(4)));

DEV unsigned short f32_bf16(float f) {
  union { float f; unsigned u; } v; v.f = f;
  unsigned r = v.u + 0x7FFFu + ((v.u >> 16) & 1u);
  return (unsigned short)(r >> 16);
}

DEV void gload16(const void* g, void* lds) {
  __builtin_amdgcn_global_load_lds((__attribute__((address_space(1))) void*)g,
                                   (__attribute__((address_space(3))) void*)lds,
                                   16, 0, 0);
}

DEV float bcast_lane(float v, int srclane) {
  union { float f; int i; } u; u.f = v;
  u.i = __builtin_amdgcn_ds_bpermute(srclane << 2, u.i);
  return u.f;
}

// 16x16x16 bf16 MFMA: A[m=lane&15][k=quad*4+j], B[k=quad*4+j][n=lane&15],
// C/D col=lane&15 row=quad*4+r. P (from S^T C-layout) feeds A directly.
DEV f32x4 mfma16_bf16(bf16x4 a, bf16x4 b, f32x4 c) {
  union { bf16x4 h; s16x4 s; } ua, ub; ua.h = a; ub.h = b;
#if __has_builtin(__builtin_amdgcn_mfma_f32_16x16x16bf16_1k)
  return __builtin_amdgcn_mfma_f32_16x16x16bf16_1k(ua.s, ub.s, c, 0, 0, 0);
#else
  f32x4 d;
  asm("v_mfma_f32_16x16x16_bf16 %0, %1, %2, %3" : "=v"(d) : "v"(ua.s), "v"(ub.s), "v"(c));
  return d;
#endif
}

// ---------------- elementwise cast fp32 -> bf16 ----------------
__global__ void cast_bf16(const float* __restrict__ x, unsigned short* __restrict__ y) {
  int i = blockIdx.x * 256 + threadIdx.x;
  float4 v = ((const float4*)x)[i];
  uint2 o;
  o.x = (unsigned)f32_bf16(v.x) | ((unsigned)f32_bf16(v.y) << 16);
  o.y = (unsigned)f32_bf16(v.z) | ((unsigned)f32_bf16(v.w) << 16);
  ((uint2*)y)[i] = o;
}

// ---------------- tiled transpose-cast: W[K][N] fp32 -> WT[N][K] bf16 ----------------
__global__ void transpose_cast(const float* __restrict__ W, unsigned short* __restrict__ WT,
                               int K, int N) {
  __shared__ float t[64][65];
  int k0 = blockIdx.x * 64, n0 = blockIdx.y * 64;
  int tn = threadIdx.x & 63, tk = threadIdx.x >> 6;
#pragma unroll
  for (int i = 0; i < 64; i += 4)
    t[tk + i][tn] = W[(size_t)(k0 + tk + i) * N + n0 + tn];
  __syncthreads();
  int k2 = (threadIdx.x & 31) * 2, n = threadIdx.x >> 5;
#pragma unroll
  for (int i = 0; i < 64; i += 8) {
    int nn = n + i;
    unsigned o = (unsigned)f32_bf16(t[k2][nn]) | ((unsigned)f32_bf16(t[k2 + 1][nn]) << 16);
    *(unsigned*)&WT[(size_t)(n0 + nn) * K + k0 + k2] = o;
  }
}

// ---------------- mask uniformity check ----------------
__global__ void mask_check(const float* __restrict__ m, int* __restrict__ flag) {
  size_t i = ((size_t)blockIdx.x * 256 + threadIdx.x) * 4;
  float4 v = *(const float4*)(m + i);
  if (v.x != 1.0f || v.y != 1.0f || v.z != 1.0f || v.w != 1.0f) atomicOr(flag, 1);
}

// ---------------- GEMM: C[M][N] = A[M][K] * BT[N][K]^T ----------------
// MODE 0: fp32 C. MODE 2: scatter Qb/Kb [b,h,s,d], VTb [b,h,d,s] (TN must be 128).
template <int MODE, int TN>
__global__ void __launch_bounds__(256) gemm_bt(const unsigned short* __restrict__ A,
                                               const unsigned short* __restrict__ BT,
                                               float* __restrict__ Cout,
                                               unsigned short* __restrict__ Qb,
                                               unsigned short* __restrict__ Kb,
                                               unsigned short* __restrict__ VTb,
                                               int M, int N, int K) {
  constexpr int NT = TN / 32;
  __shared__ __align__(16) unsigned short As[128 * 32];
  __shared__ __align__(16) unsigned short Bs[TN * 32];
  const int tid = threadIdx.x, wave = tid >> 6, lane = tid & 63;
  const int l = lane & 15, quad = lane >> 4;
  const int wm = (wave & 1) * 64, wn = (wave >> 1) * (TN >> 1);
  const int bm = blockIdx.x, bn = blockIdx.y;

  const int srowA = wave * 32 + (lane >> 2);
  const int sswzA = ((lane & 3) ^ (srowA & 3)) * 8;
  const int srowB = (TN == 128) ? srowA : (wave * 16 + (lane >> 2));
  const int sswzB = ((lane & 3) ^ (srowB & 3)) * 8;
  const unsigned short* pA = A + (size_t)(bm * 128 + srowA) * K + sswzA;
  const unsigned short* pB = BT + (size_t)(bn * TN + srowB) * K + sswzB;
  unsigned short* ldsA0 = &As[(wave * 32) * 32];
  unsigned short* ldsA1 = &As[(wave * 32 + 16) * 32];
  unsigned short* ldsB0 = &Bs[((TN == 128 ? wave * 32 : wave * 16)) * 32];
  unsigned short* ldsB1 = &Bs[(wave * 32 + 16) * 32];  // TN==128 only

  f32x4 acc[4][NT];
#pragma unroll
  for (int i = 0; i < 4; i++)
#pragma unroll
    for (int j = 0; j < NT; j++) { f32x4 z = {0.f, 0.f, 0.f, 0.f}; acc[i][j] = z; }

  for (int kt = 0; kt < K; kt += 32) {
    __syncthreads();
    gload16(pA, ldsA0);
    gload16(pA + (size_t)16 * K, ldsA1);
    gload16(pB, ldsB0);
    if (TN == 128) gload16(pB + (size_t)16 * K, ldsB1);
    pA += 32; pB += 32;
    __syncthreads();
    bf16x8 af[4], bv[NT];
#pragma unroll
    for (int mt = 0; mt < 4; mt++) {
      int r = wm + mt * 16 + l;
      af[mt] = *(const bf16x8*)&As[r * 32 + ((quad ^ (r & 3)) * 8)];
    }
#pragma unroll
    for (int nt = 0; nt < NT; nt++) {
      int r = wn + nt * 16 + l;
      bv[nt] = *(const bf16x8*)&Bs[r * 32 + ((quad ^ (r & 3)) * 8)];
    }
#pragma unroll
    for (int mt = 0; mt < 4; mt++)
#pragma unroll
      for (int nt = 0; nt < NT; nt++)
        acc[mt][nt] = __builtin_amdgcn_mfma_f32_16x16x32_bf16(af[mt], bv[nt], acc[mt][nt], 0, 0, 0);
  }

  // epilogue: C/D layout col = lane&15, row = quad*4 + r
#pragma unroll
  for (int nt = 0; nt < NT; nt++) {
    const int col = bn * TN + wn + nt * 16 + l;
#pragma unroll
    for (int mt = 0; mt < 4; mt++) {
      const int row0 = bm * 128 + wm + mt * 16 + quad * 4;
      if (MODE == 0) {
#pragma unroll
        for (int r = 0; r < 4; r++)
          Cout[(size_t)(row0 + r) * N + col] = acc[mt][nt][r];
      } else {
        const int bb = row0 >> 11, s = row0 & 2047;
        if (col < 2048) {
          unsigned short* dst = (col < 1024) ? Qb : Kb;
          const int c = col & 1023;
          const size_t off = ((size_t)(bb * 16 + (c >> 6)) * 2048 + s) * 64 + (c & 63);
#pragma unroll
          for (int r = 0; r < 4; r++)
            dst[off + (size_t)r * 64] = f32_bf16(acc[mt][nt][r]);
        } else {
          const int c = col - 2048;
          const size_t off = ((size_t)(bb * 16 + (c >> 6)) * 64 + (c & 63)) * 2048 + s;
          bf16x4 pk;
#pragma unroll
          for (int r = 0; r < 4; r++) pk[r] = (__bf16)acc[mt][nt][r];
          *(bf16x4*)&VTb[off] = pk;
        }
      }
    }
  }
}

// ---------------- fused flash attention, S^T form, P-in-registers, double-buffered ----------------
// grid 512 = 16 q-tiles x 32 (b,h); block 512 = 8 waves x 16 q-rows (16 waves/CU, 2 blocks/CU).
// blockIdx decode puts all 16 q-blocks of one (b,h) on the same XCD (bid%8 round-robin),
// so that (b,h)'s 512KB K/V stays L2-resident.
// One barrier per K-iteration: tile kt+2 is staged into the buffer consumed at iter kt,
// right after the barrier, so its loads have a full compute phase to land (no vmcnt-drain stall).
__global__ void __launch_bounds__(512, 4) attn(const unsigned short* __restrict__ Qb,
                                               const unsigned short* __restrict__ Kb,
                                               const unsigned short* __restrict__ VTb,
                                               const float* __restrict__ mask,
                                               const float* __restrict__ emb,
                                               const int* __restrict__ mflag,
                                               unsigned short* __restrict__ ctx) {
  // two buffers, each: K tile (128x64) + V^T tile (64x128)
  __shared__ __align__(16) unsigned short KV[2][16384];
  __shared__ float biasLUT[512];

  const float LOG2E = 1.4426950408889634f;
  const float c1 = 0.125f * LOG2E;
  const float C2 = 10000.0f * LOG2E;
  const int tid = threadIdx.x, wave = tid >> 6, lane = tid & 63;
  const int l = lane & 15, quad = lane >> 4;
  const int bh = blockIdx.x & 31, qt = blockIdx.x >> 5;
  const int b = bh >> 4, h = bh & 15;
  const int q0 = qt * 128;

  {
    int i = tid;  // 512 threads cover the 512-entry LUT exactly once
    int rel = i - 256;
    int rp = rel < 0 ? -rel : rel;
    int off = rp < 8 ? rp
                     : 8 + (rp >= 12) + (rp >= 16) + (rp >= 23) + (rp >= 32) +
                           (rp >= 46) + (rp >= 64) + (rp >= 91);
    int bucket = (rel > 0 ? 16 : 0) + off;
    biasLUT[i] = emb[bucket * 16 + h] * LOG2E;
  }
  const float satL = emb[15 * 16 + h] * LOG2E;
  const float satH = emb[31 * 16 + h] * LOG2E;
  const int masked = *mflag;

  const unsigned short* qb  = Qb  + ((size_t)(b * 16 + h) * 2048 + q0) * 64;
  const unsigned short* kb  = Kb  + (size_t)(b * 16 + h) * 2048 * 64;
  const unsigned short* vtb = VTb + (size_t)(b * 16 + h) * 64 * 2048;
  const float* mbase = mask + (size_t)b * 2048 * 2048;

  const int rw8 = lane >> 3, c8 = lane & 7;     // K/Q staging: 8 chunks/row
  const int rw16 = lane >> 4, c16 = lane & 15;  // V staging: 16 chunks/row

  // ---- prologue: Q -> buf1 K-region, tile0 K/V -> buf0 ----
#pragma unroll
  for (int j = 0; j < 2; j++) {
    int row = wave * 16 + j * 8 + rw8;
    gload16(qb + (size_t)row * 64 + ((c8 ^ (row & 7)) * 8), &KV[1][(wave * 16 + j * 8) * 64]);
  }
#pragma unroll
  for (int j = 0; j < 2; j++) {
    int row = wave * 16 + j * 8 + rw8;
    gload16(kb + (size_t)row * 64 + ((c8 ^ (row & 7)) * 8), &KV[0][(wave * 16 + j * 8) * 64]);
  }
#pragma unroll
  for (int j = 0; j < 2; j++) {
    int drow = wave * 8 + j * 4 + rw16;
    gload16(vtb + (size_t)drow * 2048 + ((c16 ^ (drow & 7)) * 8),
            &KV[0][8192 + (wave * 8 + j * 4) * 128]);
  }
  __syncthreads();

  // each wave reads its own 16 Q rows (self-staged region of buf1)
  bf16x8 qf[2];
#pragma unroll
  for (int ks = 0; ks < 2; ks++) {
    int row = wave * 16 + l;
    qf[ks] = *(const bf16x8*)&KV[1][row * 64 + (((ks * 4 + quad) ^ (row & 7)) * 8)];
  }
  __syncthreads();  // Q reads complete before buf1 is overwritten with tile1

  // ---- stage tile1 -> buf1 ----
#pragma unroll
  for (int j = 0; j < 2; j++) {
    int row = wave * 16 + j * 8 + rw8;
    gload16(kb + (size_t)(128 + row) * 64 + ((c8 ^ (row & 7)) * 8),
            &KV[1][(wave * 16 + j * 8) * 64]);
  }
#pragma unroll
  for (int j = 0; j < 2; j++) {
    int drow = wave * 8 + j * 4 + rw16;
    gload16(vtb + (size_t)drow * 2048 + 128 + ((c16 ^ (drow & 7)) * 8),
            &KV[1][8192 + (wave * 8 + j * 4) * 128]);
  }

  float lr = 0.f;
  f32x4 Oa[4];
#pragma unroll
  for (int dt = 0; dt < 4; dt++) { f32x4 z = {0.f, 0.f, 0.f, 0.f}; Oa[dt] = z; }

  for (int kt = 0; kt < 16; kt++) {
    const int k0 = kt * 128;
    const unsigned short* Ks  = KV[kt & 1];
    const unsigned short* VTs = KV[kt & 1] + 8192;

    // ---- S^T = K Q^T, scale+bias(+mask), exp2, pack P into A-frag regs ----
    const int d0 = k0 - q0;
    const bool sat = (d0 >= 256) || (d0 <= -256);
    const float bias_u = d0 > 0 ? satH : satL;
    const int ibase = 256 + d0 + quad * 4 - wave * 16 - l;
    bf16x4 pa[8];

#pragma unroll
    for (int ntk = 0; ntk < 8; ntk++) {
      int row = ntk * 16 + l;
      bf16x8 kf0 = *(const bf16x8*)&Ks[row * 64 + ((quad ^ (row & 7)) * 8)];
      bf16x8 kf1 = *(const bf16x8*)&Ks[row * 64 + (((4 + quad) ^ (row & 7)) * 8)];
      f32x4 s = {0.f, 0.f, 0.f, 0.f};
      s = __builtin_amdgcn_mfma_f32_16x16x32_bf16(kf0, qf[0], s, 0, 0, 0);
      s = __builtin_amdgcn_mfma_f32_16x16x32_bf16(kf1, qf[1], s, 0, 0, 0);

      const int ib = ibase + ntk * 16;
      if (!masked) {
        if (sat) {
#pragma unroll
          for (int r = 0; r < 4; r++) s[r] = fmaf(s[r], c1, bias_u);
        } else {
#pragma unroll
          for (int r = 0; r < 4; r++) s[r] = fmaf(s[r], c1, biasLUT[ib + r]);
        }
      } else {
        const int qg = q0 + wave * 16 + l;
        const int kg = k0 + ntk * 16 + quad * 4;
        float4 mv4 = *(const float4*)&mbase[(size_t)qg * 2048 + kg];
#pragma unroll
        for (int r = 0; r < 4; r++) {
          float mv = r == 0 ? mv4.x : (r == 1 ? mv4.y : (r == 2 ? mv4.z : mv4.w));
          float bias = sat ? bias_u : biasLUT[ib + r];
          s[r] = fmaf(s[r], mv * c1, fmaf(mv, C2, bias - C2));
        }
      }
      bf16x4 pk;
      float ls = 0.f;
#pragma unroll
      for (int r = 0; r < 4; r++) {
        float p = __builtin_amdgcn_exp2f(s[r]);  // softmax shift-invariance: no max needed
        ls += p;
        pk[r] = (__bf16)p;
      }
      lr += ls;
      pa[ntk] = pk;
    }

    // ---- O += P V via 16x16x16 MFMA (P straight from registers) ----
#pragma unroll
    for (int ntk = 0; ntk < 8; ntk++) {
      bf16x4 vf[4];
#pragma unroll
      for (int dt = 0; dt < 4; dt++) {
        int row = dt * 16 + l;
        int ch = (ntk * 2 + (quad >> 1)) ^ (l & 7);
        vf[dt] = *(const bf16x4*)&VTs[row * 128 + ch * 8 + (quad & 1) * 4];
      }
#pragma unroll
      for (int dt = 0; dt < 4; dt++)
        Oa[dt] = mfma16_bf16(pa[ntk], vf[dt], Oa[dt]);
    }

    // ---- one barrier: all reads of this buffer done + next tile's loads landed ----
    __syncthreads();
    if (kt + 2 < 16) {
      const int kn = (kt + 2) * 128;
      unsigned short* dst = (unsigned short*)KV[kt & 1];
#pragma unroll
      for (int j = 0; j < 2; j++) {
        int row = wave * 16 + j * 8 + rw8;
        gload16(kb + (size_t)(kn + row) * 64 + ((c8 ^ (row & 7)) * 8),
                &dst[(wave * 16 + j * 8) * 64]);
      }
#pragma unroll
      for (int j = 0; j < 2; j++) {
        int drow = wave * 8 + j * 4 + rw16;
        gload16(vtb + (size_t)drow * 2048 + kn + ((c16 ^ (drow & 7)) * 8),
                &dst[8192 + (wave * 8 + j * 4) * 128]);
      }
    }
  }

  // ---- finalize: l cross-quad sum, normalize, store ----
  float v = lr;
  v += __shfl_xor(v, 16);
  v += __shfl_xor(v, 32);
  const float inv = 1.0f / v;
#pragma unroll
  for (int r = 0; r < 4; r++) {
    float i_bc = bcast_lane(inv, quad * 4 + r);
    const int qg = q0 + wave * 16 + quad * 4 + r;
#pragma unroll
    for (int dt = 0; dt < 4; dt++)
      ctx[(size_t)(b * 2048 + qg) * 1024 + h * 64 + dt * 16 + l] =
          f32_bf16(Oa[dt][r] * i_bc);
  }
}

// ---------------- launch ----------------
extern "C" void kernel_launch(void* const* d_in, const int* in_sizes, int n_in,
                              void* d_out, int out_size, void* d_ws, size_t ws_size,
                              hipStream_t stream) {
  const float* hs   = (const float*)d_in[0];
  const float* mask = (const float*)d_in[1];
  const float* wqkv = (const float*)d_in[2];
  const float* wo   = (const float*)d_in[3];
  const float* emb  = (const float*)d_in[4];
  float* out = (float*)d_out;

  char* ws = (char*)d_ws;
  unsigned short* hB  = (unsigned short*)(ws);               //  8 MB (alias ctx)
  unsigned short* ctx = (unsigned short*)(ws);               //  alias
  unsigned short* wqT = (unsigned short*)(ws + 8388608);     //  6 MB
  unsigned short* woT = (unsigned short*)(ws + 14680064);    //  2 MB
  unsigned short* Qb  = (unsigned short*)(ws + 16777216);    //  8 MB  [b,h,s,d]
  unsigned short* Kb  = (unsigned short*)(ws + 25165824);    //  8 MB  [b,h,s,d]
  unsigned short* VTb = (unsigned short*)(ws + 33554432);    //  8 MB  [b,h,d,s]
  int* mflag          = (int*)(ws + 41943040);
  if (ws_size < 41943044) return;

  hipMemsetAsync(mflag, 0, 4, stream);
  cast_bf16<<<4096, 256, 0, stream>>>(hs, hB);
  transpose_cast<<<dim3(16, 48), 256, 0, stream>>>(wqkv, wqT, 1024, 3072);
  transpose_cast<<<dim3(16, 16), 256, 0, stream>>>(wo, woT, 1024, 1024);
  mask_check<<<8192, 256, 0, stream>>>(mask, mflag);
  gemm_bt<2, 128><<<dim3(32, 24), 256, 0, stream>>>(hB, wqT, nullptr, Qb, Kb, VTb, 4096, 3072, 1024);
  attn<<<512, 512, 0, stream>>>(Qb, Kb, VTb, mask, emb, mflag, ctx);
  gemm_bt<0, 64><<<dim3(32, 16), 256, 0, stream>>>(ctx, woT, out, nullptr, nullptr, nullptr, 4096, 1024, 1024);
}